// Round 4
// baseline (721.653 us; speedup 1.0000x reference)
//
#include <hip/hip_runtime.h>

#define VOCAB 512
#define EMB   128
#define HID   64
#define BATCH 256
#define TLEN  1024
#define CH    8               // steps per chunk (global-prefetch granularity)
#define NCH   (TLEN / CH)     // 128 chunks

typedef float v2f __attribute__((ext_vector_type(2)));

__device__ __forceinline__ float fast_tanh(float x) {
    // tanh(x) = 1 - 2/(exp(2x)+1); exact at both saturated ends.
    float e = __expf(2.0f * x);
    return 1.0f - 2.0f / (e + 1.0f);
}

// Broadcast-load one 64-float LDS row into 16 float4 registers.
// All lanes read the same row (conflict-free broadcast); compiler emits
// 16x ds_read_b128 with fine-grained lgkmcnt before each use.
__device__ __forceinline__ void bcast_load(float4* hb, const float* row) {
    const float4* hp = (const float4*)row;
    #pragma unroll
    for (int q = 0; q < 16; ++q) hb[q] = hp[q];
}

// dot(w_row[lane][:], h) from a register-resident h broadcast (hb[16]).
// Four 8-deep v2f accumulator chains.
__device__ __forceinline__ float dot64_reg(const float4* hb, const v2f* w,
                                           float init) {
    v2f a0 = v2f{init, 0.f}, a1 = v2f{0.f, 0.f};
    v2f a2 = v2f{0.f, 0.f},  a3 = v2f{0.f, 0.f};
    #pragma unroll
    for (int q = 0; q < 8; ++q) {
        float4 u = hb[2 * q];
        float4 v = hb[2 * q + 1];
        a0 = __builtin_elementwise_fma(v2f{u.x, u.y}, w[4 * q + 0], a0);
        a1 = __builtin_elementwise_fma(v2f{u.z, u.w}, w[4 * q + 1], a1);
        a2 = __builtin_elementwise_fma(v2f{v.x, v.y}, w[4 * q + 2], a2);
        a3 = __builtin_elementwise_fma(v2f{v.z, v.w}, w[4 * q + 3], a3);
    }
    return ((a0.x + a0.y) + (a1.x + a1.y)) + ((a2.x + a2.y) + (a3.x + a3.y));
}

// ---------------------------------------------------------------------------
// Kernel 1: P0[v][i] = sum_e emb[v][e]*Wih0[i][e] + bih0[i] + bhh0[i]  (fp32)
// ---------------------------------------------------------------------------
__global__ void __launch_bounds__(64) p0_kernel(
    const float* __restrict__ emb,
    const float* __restrict__ wih0,
    const float* __restrict__ bih0,
    const float* __restrict__ bhh0,
    float* __restrict__ P0)
{
    const int v = blockIdx.x;
    const int i = threadIdx.x;
    const float4* er = (const float4*)(emb  + v * EMB);
    const float4* wr = (const float4*)(wih0 + i * EMB);
    float a0 = 0.f, a1 = 0.f, a2 = 0.f, a3 = 0.f;
    #pragma unroll
    for (int k = 0; k < EMB / 4; ++k) {
        float4 e4 = er[k];
        float4 w4 = wr[k];
        a0 = fmaf(e4.x, w4.x, a0);
        a1 = fmaf(e4.y, w4.y, a1);
        a2 = fmaf(e4.z, w4.z, a2);
        a3 = fmaf(e4.w, w4.w, a3);
    }
    P0[v * HID + i] = (a0 + a1) + (a2 + a3) + bih0[i] + bhh0[i];
}

// ---------------------------------------------------------------------------
// Kernel 2 (R11): SINGLE-WAVE fused pipeline, one wave per batch element.
// R8/R10 post-mortem: the multi-wave design paid ~120cyc LDS RAW latency
// per recurrence PLUS cross-wave DS-queue interleaving, flag polling and
// ring guards (742-932 cyc/step). Here one wave computes both layers:
//   z0 = Whh0*h0b + a[t] ; h0 = tanh(z0); write+readback h0   (bcast reused
//   z1h = Whh1*h1b        <- runs while h0 readback in flight   for 2 dots)
//   p   = Wih1*h0b' + b1s ; h1 = tanh(z1h + p); write+readback h1
//   (h1 readback flight covered by next step's z0 dot + tanh)
// No flags, no barriers, no ring, no sibling-wave LDS traffic.
// ---------------------------------------------------------------------------
__global__ void __launch_bounds__(64, 1) rnn_kernel(
    const int*   __restrict__ xs,
    const float* __restrict__ P0,
    const float* __restrict__ Whh0,
    const float* __restrict__ Wih1,
    const float* __restrict__ Whh1,
    const float* __restrict__ bih1,
    const float* __restrict__ bhh1,
    const float* __restrict__ W1,
    const float* __restrict__ b1,
    const float* __restrict__ W2,
    const float* __restrict__ b2,
    float*       __restrict__ out)
{
    __shared__ float h0s[HID];          // layer-0 state handoff row
    __shared__ float h1s[HID];          // layer-1 state handoff row

    const int b    = blockIdx.x;
    const int lane = threadIdx.x;       // block == one wave

    const int* xrow = xs + b * TLEN;
    // vz == 0, but opaque to uniformity analysis -> forces VECTOR loads
    // (vmcnt path) for the x reads instead of s_load (lgkmcnt path).
    const int vz = (int)__builtin_amdgcn_mbcnt_lo(0u, 0u);

    // Three weight rows per lane, loop-invariant: 192 VGPRs.
    v2f w0[32], w1r[32], w2r[32];
    {
        const float4* p0r = (const float4*)(Whh0 + lane * HID);
        const float4* p1r = (const float4*)(Wih1 + lane * HID);
        const float4* p2r = (const float4*)(Whh1 + lane * HID);
        #pragma unroll
        for (int k = 0; k < 16; ++k) {
            float4 u = p0r[k];
            w0[2 * k]      = v2f{u.x, u.y};
            w0[2 * k + 1]  = v2f{u.z, u.w};
            float4 v = p1r[k];
            w1r[2 * k]     = v2f{v.x, v.y};
            w1r[2 * k + 1] = v2f{v.z, v.w};
            float4 t = p2r[k];
            w2r[2 * k]     = v2f{t.x, t.y};
            w2r[2 * k + 1] = v2f{t.z, t.w};
        }
    }
    const float b1s = bih1[lane] + bhh1[lane];

    // Chunk-ahead global prefetch (vmcnt path), verbatim from the R8 wave0.
    int   xv_old[CH];    // x indices of chunk k+1
    float a_old[CH];     // P0 rows for the CURRENT chunk
    #pragma unroll
    for (int i = 0; i < CH; ++i)
        xv_old[i] = xrow[CH + i + vz] & (VOCAB - 1);
    #pragma unroll
    for (int i = 0; i < CH; ++i)
        a_old[i] = P0[(xrow[i + vz] & (VOCAB - 1)) * HID + lane];

    float4 h0b[16], h1b[16];            // broadcast state, reg-resident
    #pragma unroll
    for (int q = 0; q < 16; ++q) {
        h0b[q] = float4{0.f, 0.f, 0.f, 0.f};   // h0[-1] = 0
        h1b[q] = float4{0.f, 0.f, 0.f, 0.f};   // h1[-1] = 0
    }

    #pragma unroll 1
    for (int k = 0; k < NCH; ++k) {
        // prefetch x of chunk k+2 and gather P0 rows of chunk k+1 —
        // all vector loads (vmcnt), consumed a full chunk (>2.5k cyc) later
        const int  c2  = (k + 2 < NCH) ? (k + 2) : (NCH - 1);
        const int* xp  = xrow + c2 * CH;
        int   xv_new[CH];
        float a_new[CH];
        #pragma unroll
        for (int i = 0; i < CH; ++i)
            xv_new[i] = xp[i + vz] & (VOCAB - 1);
        #pragma unroll
        for (int i = 0; i < CH; ++i)
            a_new[i] = P0[xv_old[i] * HID + lane];

        #pragma unroll
        for (int i = 0; i < CH; ++i) {
            // ---- layer 0 ----  (h1b readback from last step still in
            // flight; z0 only touches h0b/w0 so it runs underneath)
            float z0  = dot64_reg(h0b, w0, a_old[i]);
            float h0v = fast_tanh(z0);
            h0s[lane] = h0v;
            bcast_load(h0b, h0s);       // issue h0 readback (16 b128)
            // ---- layer 1 ----
            // z1h touches only h1b/w2r: executes while h0b flight drains
            float z1h = dot64_reg(h1b, w2r, 0.f);
            float p   = dot64_reg(h0b, w1r, b1s);   // waits on h0b
            float h1v = fast_tanh(z1h + p);
            h1s[lane] = h1v;
            bcast_load(h1b, h1s);       // issue h1 readback; next z0 covers
        }

        #pragma unroll
        for (int i = 0; i < CH; ++i) { a_old[i] = a_new[i]; xv_old[i] = xv_new[i]; }
    }

    // ---- MLP head: y = relu(h1 @ W1^T + b1) @ W2^T + b2 ----
    float r = 0.f;
    if (lane < 32) {
        float acc = b1[lane];
        const float* w1row = W1 + lane * HID;
        const float* hN    = h1s;              // h1[T-1] (DS in-order)
        #pragma unroll
        for (int j = 0; j < HID; ++j) acc = fmaf(w1row[j], hN[j], acc);
        r = fmaxf(acc, 0.f) * W2[lane];
    }
    #pragma unroll
    for (int off = 32; off > 0; off >>= 1) r += __shfl_down(r, off);
    if (lane == 0) out[b] = r + b2[0];
}

extern "C" void kernel_launch(void* const* d_in, const int* in_sizes, int n_in,
                              void* d_out, int out_size, void* d_ws, size_t ws_size,
                              hipStream_t stream)
{
    const int*   x    = (const int*)d_in[0];
    const float* emb  = (const float*)d_in[1];
    const float* Wih0 = (const float*)d_in[2];
    const float* Whh0 = (const float*)d_in[3];
    const float* bih0 = (const float*)d_in[4];
    const float* bhh0 = (const float*)d_in[5];
    const float* Wih1 = (const float*)d_in[6];
    const float* Whh1 = (const float*)d_in[7];
    const float* bih1 = (const float*)d_in[8];
    const float* bhh1 = (const float*)d_in[9];
    const float* W1   = (const float*)d_in[10];
    const float* b1   = (const float*)d_in[11];
    const float* W2   = (const float*)d_in[12];
    const float* b2   = (const float*)d_in[13];

    float* P0 = (float*)d_ws;   // 512*64*4 = 128 KiB scratch

    hipLaunchKernelGGL(p0_kernel, dim3(VOCAB), dim3(HID), 0, stream,
                       emb, Wih0, bih0, bhh0, P0);
    hipLaunchKernelGGL(rnn_kernel, dim3(BATCH), dim3(64), 0, stream,
                       x, P0, Whh0, Wih1, Whh1, bih1, bhh1,
                       W1, b1, W2, b2, (float*)d_out);
}

// Round 5
// 415.272 us; speedup vs baseline: 1.7378x; 1.7378x over previous
//
#include <hip/hip_runtime.h>

#define VOCAB 512
#define EMB   128
#define HID   64
#define BATCH 256
#define TLEN  1024
#define CH    8               // steps per chunk
#define NCH   (TLEN / CH)     // 128 chunks
#define RS    128             // p1 ring depth in steps
#define RCH   (RS / CH)       // 16 chunks per ring

typedef float v2f __attribute__((ext_vector_type(2)));

__device__ __forceinline__ float fast_tanh(float x) {
    // tanh(x) = 1 - 2/(exp(2x)+1); exact at both saturated ends.
    float e = __expf(2.0f * x);
    return 1.0f - 2.0f / (e + 1.0f);
}
__device__ __forceinline__ void lds_fence() {
    asm volatile("s_waitcnt lgkmcnt(0)" ::: "memory");
}
__device__ __forceinline__ void compiler_fence() {
    asm volatile("" ::: "memory");
}
__device__ __forceinline__ void nap() { __builtin_amdgcn_s_sleep(1); }

// Sum across the 4 lanes of a quad via DPP quad_perm adds.
// Pure VALU on the wave's PRIVATE SIMD -- zero LDS-pipe traffic.
// ctrl 0xB1 = quad_perm [1,0,3,2]; 0x4E = quad_perm [2,3,0,1].
__device__ __forceinline__ float quad_sum(float x) {
    int t1 = __builtin_amdgcn_update_dpp(0, __float_as_int(x), 0xB1, 0xF, 0xF, false);
    float s = x + __int_as_float(t1);
    int t2 = __builtin_amdgcn_update_dpp(0, __float_as_int(s), 0x4E, 0xF, 0xF, false);
    return s + __int_as_float(t2);
}

// 4-lane cooperative 64-dot. Lane (o=lane>>2, kg=lane&3) holds rows
// {o+16r} x cols [16kg,16kg+16) of W (w[r][c] as 8 v2f per row), and a
// 16-float h-segment in s[4]. Returns the full dot for row o+16*kg.
__device__ __forceinline__ float dot_seg(const float4 s[4], const v2f w[4][8],
                                         int kg) {
    float z0, z1, z2, z3;
    #pragma unroll
    for (int r = 0; r < 4; ++r) {
        v2f a0 = v2f{0.f, 0.f}, a1 = v2f{0.f, 0.f};
        #pragma unroll
        for (int c = 0; c < 4; ++c) {
            float4 u = s[c];
            a0 = __builtin_elementwise_fma(v2f{u.x, u.y}, w[r][2 * c],     a0);
            a1 = __builtin_elementwise_fma(v2f{u.z, u.w}, w[r][2 * c + 1], a1);
        }
        float zr = quad_sum((a0.x + a0.y) + (a1.x + a1.y));
        if (r == 0) z0 = zr; else if (r == 1) z1 = zr;
        else if (r == 2) z2 = zr; else z3 = zr;
    }
    // each lane keeps the row it owns: r == kg  (2 cndmask)
    return (kg & 1) ? ((kg & 2) ? z3 : z1) : ((kg & 2) ? z2 : z0);
}

// Per-lane weight pack for dot_seg.
__device__ __forceinline__ void load_w(v2f w[4][8], const float* __restrict__ W,
                                       int o, int kg) {
    #pragma unroll
    for (int r = 0; r < 4; ++r) {
        const float4* wr = (const float4*)(W + (o + 16 * r) * HID + 16 * kg);
        #pragma unroll
        for (int c = 0; c < 4; ++c) {
            float4 u = wr[c];
            w[r][2 * c]     = v2f{u.x, u.y};
            w[r][2 * c + 1] = v2f{u.z, u.w};
        }
    }
}

// Load this lane's 16-float segment (4x ds_read_b128, 16-lane broadcast).
__device__ __forceinline__ void seg_load(float4 s[4], const float* rowkg) {
    const float4* p = (const float4*)rowkg;
    #pragma unroll
    for (int c = 0; c < 4; ++c) s[c] = p[c];
}

// ---------------------------------------------------------------------------
// Kernel 1: P0[v][i] = sum_e emb[v][e]*Wih0[i][e] + bih0[i] + bhh0[i]  (fp32)
// ---------------------------------------------------------------------------
__global__ void __launch_bounds__(64) p0_kernel(
    const float* __restrict__ emb,
    const float* __restrict__ wih0,
    const float* __restrict__ bih0,
    const float* __restrict__ bhh0,
    float* __restrict__ P0)
{
    const int v = blockIdx.x;
    const int i = threadIdx.x;
    const float4* er = (const float4*)(emb  + v * EMB);
    const float4* wr = (const float4*)(wih0 + i * EMB);
    float a0 = 0.f, a1 = 0.f, a2 = 0.f, a3 = 0.f;
    #pragma unroll
    for (int k = 0; k < EMB / 4; ++k) {
        float4 e4 = er[k];
        float4 w4 = wr[k];
        a0 = fmaf(e4.x, w4.x, a0);
        a1 = fmaf(e4.y, w4.y, a1);
        a2 = fmaf(e4.z, w4.z, a2);
        a3 = fmaf(e4.w, w4.w, a3);
    }
    P0[v * HID + i] = (a0 + a1) + (a2 + a3) + bih0[i] + bhh0[i];
}

// ---------------------------------------------------------------------------
// Kernel 2 (R12): 2-wave pipeline, 4-lane cooperative dots.
// R8-R11 post-mortem: 16x ds_read_b128 broadcast per dot = ~192 cyc of the
// SHARED per-CU LDS pipe; 3 dots/step = ~576 cyc pipe = the 742 wall.
// Here each dot reads only a 16-float segment (4 b128) and reduces across
// the quad with DPP (private VALU). LDS: ~12 small ops/step total.
//   wave A: h0[t] = tanh(P0[x[t]] + Whh0 h0[t-1]);  p[t-1] = b1 + Wih1 h0[t-1]
//           (p-dot reuses the segment regs already loaded for z0 -> fills
//            the h0 write->readback RTT window; skewed 1 step)
//   wave C: h1[t] = tanh(p[t] + Whh1 h1[t-1]); MLP head at the end.
// ---------------------------------------------------------------------------
__global__ void __launch_bounds__(128, 1) rnn_kernel(
    const int*   __restrict__ xs,
    const float* __restrict__ P0,
    const float* __restrict__ Whh0,
    const float* __restrict__ Wih1,
    const float* __restrict__ Whh1,
    const float* __restrict__ bih1,
    const float* __restrict__ bhh1,
    const float* __restrict__ W1,
    const float* __restrict__ b1,
    const float* __restrict__ W2,
    const float* __restrict__ b2,
    float*       __restrict__ out)
{
    __shared__ float p1ring[RS][HID];   // 32 KiB (p handoff, 128-step slack)
    __shared__ float h0buf[2][HID];     // wave A private readback buffer
    __shared__ float h1buf[2][HID];     // wave C private readback buffer
    __shared__ int   flags[2];

    const int b    = blockIdx.x;
    const int tid  = threadIdx.x;
    const int wv   = tid >> 6;
    const int lane = tid & 63;
    const int o    = lane >> 2;         // output group (0..15)
    const int kg   = lane & 3;          // k-segment   (0..3)
    const int row  = o + 16 * kg;       // the output row this lane owns

    const int* xrow = xs + b * TLEN;
    // vz == 0, but opaque to uniformity analysis -> forces VECTOR loads
    // (vmcnt path) for the x reads instead of s_load (lgkmcnt path).
    const int vz = (int)__builtin_amdgcn_mbcnt_lo(0u, 0u);

    if (tid < 2) flags[tid] = 0;
    __syncthreads();                     // the ONLY barrier in the kernel

    volatile int* vf = (volatile int*)flags;

    if (wv == 0) {
        // ================= wave A: layer-0 recurrence + p projection ======
        v2f w0[4][8], wp[4][8];
        load_w(w0, Whh0, o, kg);
        load_w(wp, Wih1, o, kg);
        const float b1s = bih1[row] + bhh1[row];

        // chunk-ahead global prefetch (vmcnt), per-row P0 gather
        int   xv_old[CH];
        float a_old[CH];
        #pragma unroll
        for (int i = 0; i < CH; ++i)
            xv_old[i] = xrow[CH + i + vz] & (VOCAB - 1);
        #pragma unroll
        for (int i = 0; i < CH; ++i)
            a_old[i] = P0[(xrow[i + vz] & (VOCAB - 1)) * HID + row];

        float4 s[4];                     // h0[t-1] segment (regs)
        #pragma unroll
        for (int c = 0; c < 4; ++c) s[c] = float4{0.f, 0.f, 0.f, 0.f};

        #pragma unroll 1
        for (int k = 0; k < NCH; ++k) {
            if (k >= RCH) {              // p1ring slot-reuse guard
                while (vf[1] < k - (RCH - 1)) nap();
                compiler_fence();
            }
            const int  c2  = (k + 2 < NCH) ? (k + 2) : (NCH - 1);
            const int* xp  = xrow + c2 * CH;
            int   xv_new[CH];
            float a_new[CH];
            #pragma unroll
            for (int i = 0; i < CH; ++i)
                xv_new[i] = xp[i + vz] & (VOCAB - 1);
            #pragma unroll
            for (int i = 0; i < CH; ++i)
                a_new[i] = P0[xv_old[i] * HID + row];

            #pragma unroll
            for (int i = 0; i < CH; ++i) {
                const int t = k * CH + i;
                // layer-0 dot on h0[t-1] (register segment)
                float z  = dot_seg(s, w0, kg) + a_old[i];
                float hv = fast_tanh(z);
                h0buf[t & 1][row] = hv;              // 1 ds_write_b32
                float4 sn[4];
                seg_load(sn, &h0buf[t & 1][kg * 16]); // issue readback (4 b128)
                // p[t-1] from the OLD segment regs -- fills the RTT window.
                // t=0 writes garbage p[-1] to slot 127; overwritten at t=128
                // before wave C's flag-gated first read of that slot.
                float pv = dot_seg(s, wp, kg) + b1s;
                p1ring[(t - 1) & (RS - 1)][row] = pv;
                #pragma unroll
                for (int c = 0; c < 4; ++c) s[c] = sn[c];
            }
            lds_fence();
            if (lane == 0) vf[0] = k + 1;

            #pragma unroll
            for (int i = 0; i < CH; ++i) { a_old[i] = a_new[i]; xv_old[i] = xv_new[i]; }
        }
        // epilogue: p[TLEN-1] from the final h0 segment
        float pv = dot_seg(s, wp, kg) + b1s;
        p1ring[(TLEN - 1) & (RS - 1)][row] = pv;
        lds_fence();
        if (lane == 0) vf[0] = NCH + 1;
    } else {
        // ================= wave C: layer-1 recurrence + MLP head ==========
        v2f w2[4][8];
        load_w(w2, Whh1, o, kg);

        float4 s[4];                     // h1[t-1] segment (regs)
        #pragma unroll
        for (int c = 0; c < 4; ++c) s[c] = float4{0.f, 0.f, 0.f, 0.f};

        #pragma unroll 1
        for (int k = 0; k < NCH; ++k) {
            while (vf[0] < k + 2) nap(); // +2: p is skewed one step in wave A
            compiler_fence();
            float p[CH];                 // bulk p prefetch (stride-1 b32)
            #pragma unroll
            for (int i = 0; i < CH; ++i)
                p[i] = p1ring[(k * CH + i) & (RS - 1)][row];
            #pragma unroll
            for (int i = 0; i < CH; ++i) {
                const int t = k * CH + i;
                float z  = dot_seg(s, w2, kg) + p[i];
                float hv = fast_tanh(z);
                h1buf[t & 1][row] = hv;               // 1 ds_write_b32
                seg_load(s, &h1buf[t & 1][kg * 16]);  // readback (4 b128)
            }
            lds_fence();                 // p reads consumed, h1 writes done
            if (lane == 0) vf[1] = k + 1;
        }
        // ---- MLP head: y = relu(h1 @ W1^T + b1) @ W2^T + b2 ----
        float r = 0.f;
        if (lane < 32) {
            float acc = b1[lane];
            const float* w1row = W1 + lane * HID;
            const float* hN    = h1buf[(TLEN - 1) & 1];
            #pragma unroll
            for (int j = 0; j < HID; ++j) acc = fmaf(w1row[j], hN[j], acc);
            r = fmaxf(acc, 0.f) * W2[lane];
        }
        #pragma unroll
        for (int off = 32; off > 0; off >>= 1) r += __shfl_down(r, off);
        if (lane == 0) out[b] = r + b2[0];
    }
}

extern "C" void kernel_launch(void* const* d_in, const int* in_sizes, int n_in,
                              void* d_out, int out_size, void* d_ws, size_t ws_size,
                              hipStream_t stream)
{
    const int*   x    = (const int*)d_in[0];
    const float* emb  = (const float*)d_in[1];
    const float* Wih0 = (const float*)d_in[2];
    const float* Whh0 = (const float*)d_in[3];
    const float* bih0 = (const float*)d_in[4];
    const float* bhh0 = (const float*)d_in[5];
    const float* Wih1 = (const float*)d_in[6];
    const float* Whh1 = (const float*)d_in[7];
    const float* bih1 = (const float*)d_in[8];
    const float* bhh1 = (const float*)d_in[9];
    const float* W1   = (const float*)d_in[10];
    const float* b1   = (const float*)d_in[11];
    const float* W2   = (const float*)d_in[12];
    const float* b2   = (const float*)d_in[13];

    float* P0 = (float*)d_ws;   // 512*64*4 = 128 KiB scratch

    hipLaunchKernelGGL(p0_kernel, dim3(VOCAB), dim3(HID), 0, stream,
                       emb, Wih0, bih0, bhh0, P0);
    hipLaunchKernelGGL(rnn_kernel, dim3(BATCH), dim3(128), 0, stream,
                       x, P0, Whh0, Wih1, Whh1, bih1, bhh1,
                       W1, b1, W2, b2, (float*)d_out);
}

// Round 6
// 308.059 us; speedup vs baseline: 2.3426x; 1.3480x over previous
//
#include <hip/hip_runtime.h>

#define VOCAB 512
#define EMB   128
#define HID   64
#define BATCH 256
#define TLEN  1024
#define CH    8               // steps per chunk
#define NCH   (TLEN / CH)     // 128 chunks
#define RS    64              // ring depth in steps
#define RCH   (RS / CH)       // 8 chunks per ring
#define RW    80              // swizzled row width (floats): seg kg at 20*kg

typedef float v2f __attribute__((ext_vector_type(2)));

__device__ __forceinline__ float fast_tanh(float x) {
    // tanh(x) = 1 - 2/(exp(2x)+1); exact at both saturated ends.
    float e = __expf(2.0f * x);
    return 1.0f - 2.0f / (e + 1.0f);
}
__device__ __forceinline__ void lds_fence() {
    asm volatile("s_waitcnt lgkmcnt(0)" ::: "memory");
}
__device__ __forceinline__ void compiler_fence() {
    asm volatile("" ::: "memory");
}
__device__ __forceinline__ void nap() { __builtin_amdgcn_s_sleep(1); }

// Sum across the 4 lanes of a quad via DPP quad_perm adds (private VALU).
__device__ __forceinline__ float quad_sum(float x) {
    int t1 = __builtin_amdgcn_update_dpp(0, __float_as_int(x), 0xB1, 0xF, 0xF, false);
    float s = x + __int_as_float(t1);
    int t2 = __builtin_amdgcn_update_dpp(0, __float_as_int(s), 0x4E, 0xF, 0xF, false);
    return s + __int_as_float(t2);
}

// 4-lane cooperative 64-dot (R12, proven): lane (o=lane>>2, kg=lane&3)
// holds rows {o+16r} x cols [16kg,16kg+16) and a 16-float h segment.
// Returns the full dot for row o+16*kg.
__device__ __forceinline__ float dot_seg(const float4 s[4], const v2f w[4][8],
                                         int kg) {
    float z0, z1, z2, z3;
    #pragma unroll
    for (int r = 0; r < 4; ++r) {
        v2f a0 = v2f{0.f, 0.f}, a1 = v2f{0.f, 0.f};
        #pragma unroll
        for (int c = 0; c < 4; ++c) {
            float4 u = s[c];
            a0 = __builtin_elementwise_fma(v2f{u.x, u.y}, w[r][2 * c],     a0);
            a1 = __builtin_elementwise_fma(v2f{u.z, u.w}, w[r][2 * c + 1], a1);
        }
        float zr = quad_sum((a0.x + a0.y) + (a1.x + a1.y));
        if (r == 0) z0 = zr; else if (r == 1) z1 = zr;
        else if (r == 2) z2 = zr; else z3 = zr;
    }
    return (kg & 1) ? ((kg & 2) ? z3 : z1) : ((kg & 2) ? z2 : z0);
}

__device__ __forceinline__ void load_w(v2f w[4][8], const float* __restrict__ W,
                                       int o, int kg) {
    #pragma unroll
    for (int r = 0; r < 4; ++r) {
        const float4* wr = (const float4*)(W + (o + 16 * r) * HID + 16 * kg);
        #pragma unroll
        for (int c = 0; c < 4; ++c) {
            float4 u = wr[c];
            w[r][2 * c]     = v2f{u.x, u.y};
            w[r][2 * c + 1] = v2f{u.z, u.w};
        }
    }
}

// Load this lane's 16-float segment (4x ds_read_b128). With the RW=80
// skew, the 4 kg-addresses land in disjoint bank quads -> conflict-free
// (fixes R12's 2.1M SQ_LDS_BANK_CONFLICT).
__device__ __forceinline__ void seg_load(float4 s[4], const float* rowkg) {
    const float4* p = (const float4*)rowkg;
    #pragma unroll
    for (int c = 0; c < 4; ++c) s[c] = p[c];
}

// ---------------------------------------------------------------------------
// Kernel 1: P0[v][i] = sum_e emb[v][e]*Wih0[i][e] + bih0[i] + bhh0[i]  (fp32)
// ---------------------------------------------------------------------------
__global__ void __launch_bounds__(64) p0_kernel(
    const float* __restrict__ emb,
    const float* __restrict__ wih0,
    const float* __restrict__ bih0,
    const float* __restrict__ bhh0,
    float* __restrict__ P0)
{
    const int v = blockIdx.x;
    const int i = threadIdx.x;
    const float4* er = (const float4*)(emb  + v * EMB);
    const float4* wr = (const float4*)(wih0 + i * EMB);
    float a0 = 0.f, a1 = 0.f, a2 = 0.f, a3 = 0.f;
    #pragma unroll
    for (int k = 0; k < EMB / 4; ++k) {
        float4 e4 = er[k];
        float4 w4 = wr[k];
        a0 = fmaf(e4.x, w4.x, a0);
        a1 = fmaf(e4.y, w4.y, a1);
        a2 = fmaf(e4.z, w4.z, a2);
        a3 = fmaf(e4.w, w4.w, a3);
    }
    P0[v * HID + i] = (a0 + a1) + (a2 + a3) + bih0[i] + bhh0[i];
}

// ---------------------------------------------------------------------------
// Kernel 2 (R13): R8's proven 3-wave topology (one dot per wave per step =
// minimum per-wave serial chain) + R12's proven 4-b128 segment dot
// (readback RTT ~300 -> ~156 cyc) + bank-quad skew (RW=80).
//   wave0: h0[t] = tanh(P0[x[t]] + Whh0 h0[t-1])   readback: 4 b128
//   wave1: p1[t] = b1 + Wih1 h0[t]                 reads: 4 b128 (pipelined)
//   wave2: h1[t] = tanh(p1[t] + Whh1 h1[t-1])      readback: 4 b128
// ---------------------------------------------------------------------------
__global__ void __launch_bounds__(192, 1) rnn_kernel(
    const int*   __restrict__ xs,
    const float* __restrict__ P0,
    const float* __restrict__ Whh0,
    const float* __restrict__ Wih1,
    const float* __restrict__ Whh1,
    const float* __restrict__ bih1,
    const float* __restrict__ bhh1,
    const float* __restrict__ W1,
    const float* __restrict__ b1,
    const float* __restrict__ W2,
    const float* __restrict__ b2,
    float*       __restrict__ out)
{
    __shared__ float h0ring[RS][RW];    // 20 KiB, swizzled rows
    __shared__ float p1ring[RS][HID];   // 16 KiB, plain rows (b32 per lane)
    __shared__ float h1buf[2][RW];      // swizzled
    __shared__ int   flags[3];

    const int b    = blockIdx.x;
    const int tid  = threadIdx.x;
    const int wv   = tid >> 6;
    const int lane = tid & 63;
    const int o    = lane >> 2;         // output group (0..15)
    const int kg   = lane & 3;          // k-segment   (0..3)
    const int row  = o + 16 * kg;       // output row this lane owns
    const int wrs  = 20 * kg + o;       // swizzled write slot for `row`

    const int* xrow = xs + b * TLEN;
    // vz == 0, but opaque to uniformity analysis -> forces VECTOR loads
    // (vmcnt path) for the x reads instead of s_load (lgkmcnt path).
    const int vz = (int)__builtin_amdgcn_mbcnt_lo(0u, 0u);

    if (tid < 3) flags[tid] = 0;
    __syncthreads();                     // the ONLY barrier in the kernel

    volatile int* vf = (volatile int*)flags;

    if (wv == 0) {
        // ================= wave0: layer-0 recurrence ======================
        v2f w0[4][8];
        load_w(w0, Whh0, o, kg);

        int   xv_old[CH];
        float a_old[CH];
        #pragma unroll
        for (int i = 0; i < CH; ++i)
            xv_old[i] = xrow[CH + i + vz] & (VOCAB - 1);
        #pragma unroll
        for (int i = 0; i < CH; ++i)
            a_old[i] = P0[(xrow[i + vz] & (VOCAB - 1)) * HID + row];

        float4 s0[4];                    // h0[t-1] segment (regs)
        #pragma unroll
        for (int c = 0; c < 4; ++c) s0[c] = float4{0.f, 0.f, 0.f, 0.f};

        #pragma unroll 1
        for (int k = 0; k < NCH; ++k) {
            if (k >= RCH) {              // h0ring slot-reuse guard (wave1)
                while (vf[1] < k - (RCH - 1)) nap();
                compiler_fence();
            }
            const int  c2  = (k + 2 < NCH) ? (k + 2) : (NCH - 1);
            const int* xp  = xrow + c2 * CH;
            int   xv_new[CH];
            float a_new[CH];
            #pragma unroll
            for (int i = 0; i < CH; ++i)
                xv_new[i] = xp[i + vz] & (VOCAB - 1);
            #pragma unroll
            for (int i = 0; i < CH; ++i)
                a_new[i] = P0[xv_old[i] * HID + row];

            const int base = (k & (RCH - 1)) * CH;
            #pragma unroll
            for (int i = 0; i < CH; ++i) {
                float z  = dot_seg(s0, w0, kg) + a_old[i];
                float hv = fast_tanh(z);
                h0ring[base + i][wrs] = hv;               // 1 ds_write_b32
                seg_load(s0, &h0ring[base + i][20 * kg]); // readback, 4 b128
            }
            lds_fence();
            if (lane == 0) vf[0] = k + 1;

            #pragma unroll
            for (int i = 0; i < CH; ++i) { a_old[i] = a_new[i]; xv_old[i] = xv_new[i]; }
        }
    } else if (wv == 1) {
        // ================= wave1: p1 projection (no recurrence) ===========
        v2f wp[4][8];
        load_w(wp, Wih1, o, kg);
        const float b1s = bih1[row] + bhh1[row];

        #pragma unroll 1
        for (int k = 0; k < NCH; ++k) {
            while (vf[0] < k + 1) nap();
            if (k >= RCH) { while (vf[2] < k - (RCH - 1)) nap(); }
            compiler_fence();
            const int base = (k & (RCH - 1)) * CH;
            float4 c0[4];
            seg_load(c0, &h0ring[base][20 * kg]);
            #pragma unroll
            for (int i = 0; i < CH; ++i) {
                float4 nx[4];
                if (i < CH - 1) seg_load(nx, &h0ring[base + i + 1][20 * kg]);
                float pv = dot_seg(c0, wp, kg) + b1s;
                p1ring[base + i][row] = pv;
                if (i < CH - 1) {
                    #pragma unroll
                    for (int c = 0; c < 4; ++c) c0[c] = nx[c];
                }
            }
            lds_fence();
            if (lane == 0) vf[1] = k + 1;
        }
    } else {
        // ================= wave2: layer-1 recurrence + MLP head ===========
        v2f w2[4][8];
        load_w(w2, Whh1, o, kg);

        float4 s1[4];
        #pragma unroll
        for (int c = 0; c < 4; ++c) s1[c] = float4{0.f, 0.f, 0.f, 0.f};

        #pragma unroll 1
        for (int k = 0; k < NCH; ++k) {
            while (vf[1] < k + 1) nap();
            compiler_fence();
            const int base = (k & (RCH - 1)) * CH;
            float p[CH];                 // bulk p prefetch (b32, 2/bank free)
            #pragma unroll
            for (int i = 0; i < CH; ++i) p[i] = p1ring[base + i][row];
            #pragma unroll
            for (int i = 0; i < CH; ++i) {
                const int t = k * CH + i;
                float z  = dot_seg(s1, w2, kg) + p[i];
                float hv = fast_tanh(z);
                h1buf[t & 1][wrs] = hv;                   // 1 ds_write_b32
                seg_load(s1, &h1buf[t & 1][20 * kg]);     // readback, 4 b128
            }
            lds_fence();                 // p reads consumed, h1 writes done
            if (lane == 0) vf[2] = k + 1;
        }
        // ---- MLP head: y = relu(h1 @ W1^T + b1) @ W2^T + b2 ----
        float r = 0.f;
        if (lane < 32) {
            float acc = b1[lane];
            const float* w1row = W1 + lane * HID;
            const float* hN    = h1buf[(TLEN - 1) & 1];
            #pragma unroll
            for (int j = 0; j < HID; ++j)
                acc = fmaf(w1row[j], hN[20 * (j >> 4) + (j & 15)], acc);
            r = fmaxf(acc, 0.f) * W2[lane];
        }
        #pragma unroll
        for (int off = 32; off > 0; off >>= 1) r += __shfl_down(r, off);
        if (lane == 0) out[b] = r + b2[0];
    }
}

extern "C" void kernel_launch(void* const* d_in, const int* in_sizes, int n_in,
                              void* d_out, int out_size, void* d_ws, size_t ws_size,
                              hipStream_t stream)
{
    const int*   x    = (const int*)d_in[0];
    const float* emb  = (const float*)d_in[1];
    const float* Wih0 = (const float*)d_in[2];
    const float* Whh0 = (const float*)d_in[3];
    const float* bih0 = (const float*)d_in[4];
    const float* bhh0 = (const float*)d_in[5];
    const float* Wih1 = (const float*)d_in[6];
    const float* Whh1 = (const float*)d_in[7];
    const float* bih1 = (const float*)d_in[8];
    const float* bhh1 = (const float*)d_in[9];
    const float* W1   = (const float*)d_in[10];
    const float* b1   = (const float*)d_in[11];
    const float* W2   = (const float*)d_in[12];
    const float* b2   = (const float*)d_in[13];

    float* P0 = (float*)d_ws;   // 512*64*4 = 128 KiB scratch

    hipLaunchKernelGGL(p0_kernel, dim3(VOCAB), dim3(HID), 0, stream,
                       emb, Wih0, bih0, bhh0, P0);
    hipLaunchKernelGGL(rnn_kernel, dim3(BATCH), dim3(192), 0, stream,
                       x, P0, Whh0, Wih1, Whh1, bih1, bhh1,
                       W1, b1, W2, b2, (float*)d_out);
}